// Round 1
// baseline (4155.031 us; speedup 1.0000x reference)
//
#include <hip/hip_runtime.h>

// DTW accumulated-cost, output = last column. N=65536 rows (input), K=512 cols (kernel).
// Anti-diagonal recurrence with E[j]=min(A_t[j],A_{t-1}[j]):
//   A_{t+1}[j] = min(A_t[j], E_t[j-1]) + (k[j]-x[i])^2 ,  i = t+1-j
// 4 waves (one per SIMD) split j into 128-wide bands; skewed-chunk barrier
// pipeline passes the band-boundary E value through LDS rings.
// Edge cells are eliminated by padding x with 1e20 (d -> +inf, propagates safely).

#define K_LEN 512
#define N_LEN 65536
#define PAD_L 512
#define PAD_R 1024
#define XPAD_TOTAL (PAD_L + N_LEN + PAD_R) // 67072 floats = 268288 B of d_ws
#define BIGX 1e20f
#define NCHUNK 1032                        // 1032*64 = 66048 >= N+K-1 = 66047 diagonals
#define RING 256                           // ring entries per boundary buffer (4 chunks)

__global__ void dtw_pad_kernel(const float* __restrict__ x, float* __restrict__ xpad) {
    int i = blockIdx.x * blockDim.x + threadIdx.x;
    if (i < XPAD_TOTAL) {
        int j = i - PAD_L;
        xpad[i] = (j >= 0 && j < N_LEN) ? x[j] : BIGX;
    }
}

__global__ __launch_bounds__(256, 1) void dtw_main(const float* __restrict__ xpad,
                                                   const float* __restrict__ kern,
                                                   float* __restrict__ out) {
    __shared__ float lds[5 * RING]; // buf[w]=w*RING written by wave w (buf3 = wave-3 out staging),
                                    // INIT buffer at 4*RING read by wave 0
    const float INFV = __builtin_inff();
    const int tid  = threadIdx.x;
    const int w    = __builtin_amdgcn_readfirstlane(tid) >> 6; // wave id, uniform SGPR
    const int lane = tid & 63;

    // LDS init: all INF; INIT[255] = 0.0 is the DP seed ac[-1][-1]=0 (read by wave 0 at t=0)
    for (int i = tid; i < 5 * RING; i += 256)
        lds[i] = (i == 4 * RING + RING - 1) ? 0.0f : INFV;
    __syncthreads();

    const int jbase = w * 128;
    const int j0    = jbase + 2 * lane;     // slot-0 column; slot-1 = j0+1
    const float k0  = kern[j0];
    const float k1  = kern[j0 + 1];

    // per-lane x stream: fresh (slot-0) x at diagonal t is xl[t]
    const float* xl = xpad + (PAD_L - j0);
    float xp = xl[-1];                      // slot-1 x entering t=0 (index >= 1, in left pad)

    float* ldsOut       = lds + w * RING;
    const float* ldsIn  = (w == 0) ? (lds + 4 * RING) : (lds + (w - 1) * RING);

    float A0 = INFV, A1 = INFV, E0 = INFV, E1 = INFV;

    for (int S = 0; S < NCHUNK + 3; ++S) {
        const int c = S - w;                // chunk index for this wave (skewed pipeline)
        if (c >= 0 && c < NCHUNK) {
            const int t0 = c * 64;
            const int rb = (c & 3) * 64;    // ring base slot
            const float bin0 = ldsIn[(rb + RING - 1) & (RING - 1)]; // boundary for r=0 (slot (t0-1)&255)
            const float* xc = xl + t0;
#pragma unroll
            for (int r = 0; r < 64; ++r) {
                const float xf  = xc[r];                       // x for slot 0 (i = t - j0)
                const float bin = (r == 0) ? bin0 : ldsIn[rb + r - 1]; // E_{t-1}[jbase-1]
                // slot0 shifted E: lane l <- lane l-1's E1; lane 0 <- bin (dpp old, bound_ctrl=0)
                const float esh0 = __int_as_float(__builtin_amdgcn_update_dpp(
                    __float_as_int(bin), __float_as_int(E1), 0x138 /*wave_shr:1*/, 0xF, 0xF, false));
                const float esh1 = E0;
                float d0 = k0 - xf; d0 *= d0;
                float d1 = k1 - xp; d1 *= d1;
                const float na0 = fminf(A0, esh0) + d0;
                const float na1 = fminf(A1, esh1) + d1;
                const float ne0 = fminf(na0, A0);
                const float ne1 = fminf(na1, A1);
                A0 = na0; A1 = na1; E0 = ne0; E1 = ne1; xp = xf;
                // publish top-boundary E (waves 0-2) / output A_t[511] (wave 3) from lane 63
                const float bv = (w == 3) ? na1 : ne1;
                if (lane == 63) ldsOut[rb + r] = bv;
            }
            if (w == 3) { // coalesced store of this chunk's 64 outputs
                const float ov = ldsOut[rb + lane];
                const int oi = t0 + lane - (K_LEN - 1);
                if (oi >= 0 && oi < N_LEN) out[oi] = ov;
            }
        }
        if (S == 0 && tid == 0) lds[4 * RING + RING - 1] = INFV; // retire the seed before ring wraps
        __syncthreads();
    }
}

extern "C" void kernel_launch(void* const* d_in, const int* in_sizes, int n_in,
                              void* d_out, int out_size, void* d_ws, size_t ws_size,
                              hipStream_t stream) {
    const float* x = (const float*)d_in[0];   // input, 65536 fp32
    const float* k = (const float*)d_in[1];   // kernel, 512 fp32
    float* xpad = (float*)d_ws;               // needs 268288 B of scratch
    float* out  = (float*)d_out;              // 65536 fp32
    dtw_pad_kernel<<<(XPAD_TOTAL + 255) / 256, 256, 0, stream>>>(x, xpad);
    dtw_main<<<1, 256, 0, stream>>>(xpad, k, out);
}

// Round 2
// 2128.835 us; speedup vs baseline: 1.9518x; 1.9518x over previous
//
#include <hip/hip_runtime.h>

// DTW accumulated-cost, output = last column. N=65536 rows (input), K=512 cols (kernel).
// Anti-diagonal recurrence with E[j]=min(A_t[j],A_{t-1}[j]):
//   A_{t+1}[j] = min(A_t[j], E_t[j-1]) + (k[j]-x[i])^2 ,  i = t+1-j
// 4 waves (one per SIMD) split j into 128-wide bands (j = 128w + 2*lane + slot);
// skewed-chunk barrier pipeline passes band-boundary E values through LDS rings.
// R2: batch-prefetch x (global) and boundary (LDS) into register arrays per
// 64-diagonal chunk — R1 serialized a ~120cyc ds_read + ~200cyc global load
// into every diagonal's dependency chain (12 VGPRs => rolled loop).

#define K_LEN 512
#define N_LEN 65536
#define PAD_L 512
#define PAD_R 1024
#define XPAD_TOTAL (PAD_L + N_LEN + PAD_R) // 67072 floats = 268288 B of d_ws
#define BIGX 1e20f
#define NCHUNK 1032                        // 1032*64 = 66048 >= N+K-1 = 66047 diagonals
#define RING 256                           // ring entries per boundary buffer (4 chunks)

__global__ void dtw_pad_kernel(const float* __restrict__ x, float* __restrict__ xpad) {
    int i = blockIdx.x * blockDim.x + threadIdx.x;
    if (i < XPAD_TOTAL) {
        int j = i - PAD_L;
        xpad[i] = (j >= 0 && j < N_LEN) ? x[j] : BIGX;
    }
}

template <bool LAST>
__device__ __forceinline__ void dtw_chunk(int c, const float* __restrict__ xl,
                                          const float* __restrict__ ldsIn,
                                          float* __restrict__ ldsOut,
                                          float k0, float k1,
                                          float& A0, float& A1, float& E0, float& E1,
                                          float& xp, int lane, float* __restrict__ out) {
    const int t0 = c * 64;
    const int rb = (c & 3) * 64;

    // Batch prefetch: 64 x values (global, independent, all outstanding at once)
    float xv[64];
#pragma unroll
    for (int r = 0; r < 64; ++r) xv[r] = xl[t0 + r];

    // Batch prefetch: 64 boundary values (LDS broadcast reads, pipelined)
    float binv[64];
    binv[0] = ldsIn[(rb + RING - 1) & (RING - 1)]; // slot (t0-1) mod 256
#pragma unroll
    for (int r = 1; r < 64; ++r) binv[r] = ldsIn[rb + r - 1];

    float keep[64]; // lane 63's boundary E (waves 0-2) or output A[511] (wave 3)

#pragma unroll
    for (int r = 0; r < 64; ++r) {
        const float xf = xv[r]; // x for slot 0 (i = t - j0)
        // slot0 shifted E: lane l <- lane l-1's E1; lane 0 <- binv[r] (dpp old, bound_ctrl=0)
        const float esh0 = __int_as_float(__builtin_amdgcn_update_dpp(
            __float_as_int(binv[r]), __float_as_int(E1), 0x138 /*wave_shr:1*/, 0xF, 0xF, false));
        const float esh1 = E0;
        float d0 = k0 - xf; d0 *= d0;
        float d1 = k1 - xp; d1 *= d1;
        const float na0 = fminf(A0, esh0) + d0;
        const float na1 = fminf(A1, esh1) + d1;
        const float ne0 = fminf(na0, A0);
        const float ne1 = fminf(na1, A1);
        keep[r] = LAST ? na1 : ne1;
        A0 = na0; A1 = na1; E0 = ne0; E1 = ne1; xp = xf;
    }

    // Single exec-masked batch publish from lane 63
    if (lane == 63) {
#pragma unroll
        for (int r = 0; r < 64; ++r) ldsOut[rb + r] = keep[r];
    }

    if (LAST) { // coalesced store of this chunk's 64 outputs (same-wave DS in-order)
        const float ov = ldsOut[rb + lane];
        const int oi = t0 + lane - (K_LEN - 1);
        if (oi >= 0 && oi < N_LEN) out[oi] = ov;
    }
}

__global__ __launch_bounds__(256, 1) void dtw_main(const float* __restrict__ xpad,
                                                   const float* __restrict__ kern,
                                                   float* __restrict__ out) {
    __shared__ float lds[5 * RING]; // buf[w]=w*RING written by wave w (buf3 = wave-3 out staging),
                                    // INIT buffer at 4*RING read by wave 0
    const float INFV = __builtin_inff();
    const int tid  = threadIdx.x;
    const int w    = __builtin_amdgcn_readfirstlane(tid) >> 6; // wave id, uniform SGPR
    const int lane = tid & 63;

    // LDS init: all INF; INIT[255] = 0.0 is the DP seed ac[-1][-1]=0 (read by wave 0 at t=0)
    for (int i = tid; i < 5 * RING; i += 256)
        lds[i] = (i == 4 * RING + RING - 1) ? 0.0f : INFV;
    __syncthreads();

    const int j0 = w * 128 + 2 * lane;      // slot-0 column; slot-1 = j0+1
    const float k0 = kern[j0];
    const float k1 = kern[j0 + 1];

    // per-lane x stream: fresh (slot-0) x at diagonal t is xl[t]
    const float* xl = xpad + (PAD_L - j0);
    float xp = xl[-1];                      // slot-1 x entering t=0

    float* ldsOut      = lds + w * RING;
    const float* ldsIn = (w == 0) ? (lds + 4 * RING) : (lds + (w - 1) * RING);

    float A0 = INFV, A1 = INFV, E0 = INFV, E1 = INFV;

    for (int S = 0; S < NCHUNK + 3; ++S) {
        const int c = S - w;                // chunk index for this wave (skewed pipeline)
        if (c >= 0 && c < NCHUNK) {
            if (w == 3)
                dtw_chunk<true>(c, xl, ldsIn, ldsOut, k0, k1, A0, A1, E0, E1, xp, lane, out);
            else
                dtw_chunk<false>(c, xl, ldsIn, ldsOut, k0, k1, A0, A1, E0, E1, xp, lane, out);
        }
        if (S == 0 && tid == 0) lds[4 * RING + RING - 1] = INFV; // retire the seed before ring wraps
        __syncthreads();
    }
}

extern "C" void kernel_launch(void* const* d_in, const int* in_sizes, int n_in,
                              void* d_out, int out_size, void* d_ws, size_t ws_size,
                              hipStream_t stream) {
    const float* x = (const float*)d_in[0];   // input, 65536 fp32
    const float* k = (const float*)d_in[1];   // kernel, 512 fp32
    float* xpad = (float*)d_ws;               // needs 268288 B of scratch
    float* out  = (float*)d_out;              // 65536 fp32
    dtw_pad_kernel<<<(XPAD_TOTAL + 255) / 256, 256, 0, stream>>>(x, xpad);
    dtw_main<<<1, 256, 0, stream>>>(xpad, k, out);
}